// Round 1
// baseline (153.298 us; speedup 1.0000x reference)
//
#include <hip/hip_runtime.h>
#include <math.h>

#define NB 256
#define ND 768
#define MARGIN_F 0.2f

// ---------------- Kernel A: pairwise Euclidean distance, 8 rows/block ----------------
__global__ __launch_bounds__(256) void dist_kernel(const float* __restrict__ X,
                                                   float* __restrict__ Dout) {
    __shared__ float xi[8][ND];
    const int i0 = blockIdx.x * 8;

    // cooperatively stage 8 rows (6144 floats = 1536 float4) into LDS
    const float4* src = (const float4*)(X + (size_t)i0 * ND);
    float4* dst = (float4*)(&xi[0][0]);
    for (int t = threadIdx.x; t < (8 * ND) / 4; t += 256) dst[t] = src[t];
    __syncthreads();

    const int j = threadIdx.x;
    const float4* xj = (const float4*)(X + (size_t)j * ND);

    float acc[8];
#pragma unroll
    for (int r = 0; r < 8; ++r) acc[r] = 0.0f;

    for (int t = 0; t < ND / 4; ++t) {
        const float4 v = xj[t];
#pragma unroll
        for (int r = 0; r < 8; ++r) {
            const float4 w = *(const float4*)(&xi[r][4 * t]);  // LDS broadcast
            const float a = w.x - v.x;
            const float b = w.y - v.y;
            const float c = w.z - v.z;
            const float d = w.w - v.w;
            acc[r] += a * a + b * b + c * c + d * d;
        }
    }

#pragma unroll
    for (int r = 0; r < 8; ++r) {
        const float d2 = acc[r];
        Dout[(size_t)(i0 + r) * NB + j] = (d2 > 0.0f) ? sqrtf(d2) : 0.0f;
    }
}

// ---------------- Kernel B: triplet loss over pairs (j<k) for row i ----------------
__global__ __launch_bounds__(256) void triplet_kernel(const float* __restrict__ dE,
                                                      const float* __restrict__ dG,
                                                      float* __restrict__ partials) {
    __shared__ float E[NB];
    __shared__ float G[NB];
    const int i = blockIdx.x;
    const int tid = threadIdx.x;

    E[tid] = dE[(size_t)i * NB + tid];
    G[tid] = dG[(size_t)i * NB + tid];
    __syncthreads();

    const int k = tid;
    const float ek = E[k];
    const float gk = G[k];
    const bool k_ok = (k != i);

    float local = 0.0f;
    for (int j = 0; j < NB; ++j) {
        const float ej = E[j];  // uniform addr -> LDS broadcast
        const float gj = G[j];
        const float diff = gj - gk;
        const float lp = fmaxf(diff + MARGIN_F, 0.0f);   // e_ij < e_ik
        const float ln = fmaxf(MARGIN_F - diff, 0.0f);   // e_ik < e_ij
        const float le = fabsf(diff);                    // tie
        float l = (ej < ek) ? lp : ((ek < ej) ? ln : le);
        const bool active = (k > j) & k_ok & (j != i);
        local += active ? l : 0.0f;
    }

    // wave (64-lane) shuffle reduce, then cross-wave via LDS
    for (int off = 32; off > 0; off >>= 1) local += __shfl_down(local, off, 64);
    __shared__ float wsum[4];
    const int wid = tid >> 6;
    const int lane = tid & 63;
    if (lane == 0) wsum[wid] = local;
    __syncthreads();
    if (tid == 0) partials[i] = wsum[0] + wsum[1] + wsum[2] + wsum[3];
}

// ---------------- Kernel C: final reduction (double) + normalize ----------------
__global__ __launch_bounds__(256) void reduce_kernel(const float* __restrict__ partials,
                                                     float* __restrict__ out) {
    const int tid = threadIdx.x;
    double v = (double)partials[tid];
    for (int off = 32; off > 0; off >>= 1) v += __shfl_down(v, off, 64);
    __shared__ double ws4[4];
    const int wid = tid >> 6;
    const int lane = tid & 63;
    if (lane == 0) ws4[wid] = v;
    __syncthreads();
    if (tid == 0) {
        const double total = ws4[0] + ws4[1] + ws4[2] + ws4[3];
        out[0] = (float)(total / 8290560.0);  // 256*255*254/2
    }
}

extern "C" void kernel_launch(void* const* d_in, const int* in_sizes, int n_in,
                              void* d_out, int out_size, void* d_ws, size_t ws_size,
                              hipStream_t stream) {
    const float* img = (const float*)d_in[0];  // img_tokens (256,768)
    const float* ehr = (const float*)d_in[1];  // ehr_tokens (256,768)
    float* out = (float*)d_out;

    float* dE = (float*)d_ws;            // 256*256 floats  (ehr distances)
    float* dG = dE + NB * NB;            // 256*256 floats  (img distances)
    float* partials = dG + NB * NB;      // 256 floats

    dist_kernel<<<dim3(NB / 8), 256, 0, stream>>>(ehr, dE);
    dist_kernel<<<dim3(NB / 8), 256, 0, stream>>>(img, dG);
    triplet_kernel<<<NB, 256, 0, stream>>>(dE, dG, partials);
    reduce_kernel<<<1, 256, 0, stream>>>(partials, out);
}

// Round 2
// 23.137 us; speedup vs baseline: 6.6257x; 6.6257x over previous
//
#include <hip/hip_runtime.h>
#include <math.h>

#define NB 256
#define ND 768
#define MARGIN_F 0.2f
#define KC 256            // k-chunk staged in LDS
#define PADF 4            // +16B row padding -> conflict-free b128 reads
#define NTILES 136        // 16*17/2 triangular 16x16 tiles

// ---------------- Kernel A: both pairwise-distance matrices, tiled ----------------
// Block = one 16x16 output tile (ti<=tj), mirrored write for ti<tj.
// bid < NTILES -> img matrix; else ehr matrix.
__global__ __launch_bounds__(256) void dist_kernel(const float* __restrict__ Ximg,
                                                   const float* __restrict__ Xehr,
                                                   float* __restrict__ dG,
                                                   float* __restrict__ dE) {
    __shared__ float A[16][KC + PADF];
    __shared__ float B[16][KC + PADF];

    int t = blockIdx.x;
    const int m = (t >= NTILES) ? 1 : 0;
    t -= m * NTILES;
    const float* __restrict__ X = m ? Xehr : Ximg;
    float* __restrict__ D = m ? dE : dG;

    // triangular decode t -> (ti, tj), ti <= tj  (uniform scalar loop)
    int ti = 0;
    while (t >= 16 - ti) { t -= 16 - ti; ++ti; }
    const int tj = ti + t;

    const int tid = threadIdx.x;
    const int li = tid >> 4;    // row within tile
    const int lj = tid & 15;    // col within tile

    float acc = 0.0f;

    for (int c = 0; c < ND; c += KC) {
        // cooperative stage: 16 rows x KC floats per side, coalesced float4
        const int r0 = tid >> 6;        // 0..3
        const int f = tid & 63;         // float4 index within row chunk
#pragma unroll
        for (int rr = 0; rr < 16; rr += 4) {
            const int row = rr + r0;
            float4 va = *(const float4*)(&X[(size_t)(ti * 16 + row) * ND + c + f * 4]);
            *(float4*)(&A[row][f * 4]) = va;
            float4 vb = *(const float4*)(&X[(size_t)(tj * 16 + row) * ND + c + f * 4]);
            *(float4*)(&B[row][f * 4]) = vb;
        }
        __syncthreads();

#pragma unroll 8
        for (int kk = 0; kk < KC; kk += 4) {
            const float4 a = *(const float4*)(&A[li][kk]);
            const float4 b = *(const float4*)(&B[lj][kk]);
            const float d0 = a.x - b.x;
            const float d1 = a.y - b.y;
            const float d2 = a.z - b.z;
            const float d3 = a.w - b.w;
            acc += d0 * d0 + d1 * d1 + d2 * d2 + d3 * d3;
        }
        __syncthreads();
    }

    const float dval = (acc > 0.0f) ? sqrtf(acc) : 0.0f;
    const int gi = ti * 16 + li;
    const int gj = tj * 16 + lj;
    D[(size_t)gi * NB + gj] = dval;
    if (ti != tj) D[(size_t)gj * NB + gi] = dval;   // mirror
}

// ---------------- Kernel B: triplet loss, ordered-pair form ----------------
// term(j,k) is symmetric in j<->k, so sum over ALL ordered pairs j!=k (both != i)
// equals 2x the reference sum over j<k. j==k contributes exactly 0 (tie, |0|).
// j==i term is exactly relu(M - g_ik) (since d_ii = 0) -> post-loop correction.
// Grid: 512 blocks = (i, half of j-range). 2 blocks/CU.
__global__ __launch_bounds__(256) void triplet_kernel(const float* __restrict__ dE,
                                                      const float* __restrict__ dG,
                                                      float* __restrict__ partials) {
    __shared__ float E[NB];
    __shared__ float G[NB];
    const int i = blockIdx.x >> 1;
    const int half = blockIdx.x & 1;
    const int tid = threadIdx.x;

    E[tid] = dE[(size_t)i * NB + tid];
    G[tid] = dG[(size_t)i * NB + tid];
    __syncthreads();

    const int k = tid;
    const float ek = E[k];
    const float gk = G[k];

    float local = 0.0f;
    const int j0 = half << 7;
#pragma unroll 4
    for (int jj = 0; jj < 128; ++jj) {
        const int j = j0 + jj;
        const float ej = E[j];      // uniform address -> LDS broadcast
        const float gj = G[j];
        const float diff = gj - gk;
        const float a = diff + MARGIN_F;      // e_ij < e_ik
        const float b = MARGIN_F - diff;      // e_ik < e_ij
        const float cc = fabsf(diff);         // tie (incl. j==k -> 0)
        const float sel = (ej < ek) ? a : ((ek < ej) ? b : cc);
        local += fmaxf(sel, 0.0f);
    }
    // remove the j==i term computed in the loop (valid only for threads k != i)
    if (((i >> 7) == half) && (k != i)) local -= fmaxf(MARGIN_F - gk, 0.0f);
    if (k == i) local = 0.0f;   // k must differ from i

    // wave reduce + cross-wave
    for (int off = 32; off > 0; off >>= 1) local += __shfl_down(local, off, 64);
    __shared__ float wsum[4];
    const int wid = tid >> 6;
    const int lane = tid & 63;
    if (lane == 0) wsum[wid] = local;
    __syncthreads();
    if (tid == 0) partials[blockIdx.x] = wsum[0] + wsum[1] + wsum[2] + wsum[3];
}

// ---------------- Kernel C: final reduction (double) + normalize ----------------
__global__ __launch_bounds__(256) void reduce_kernel(const float* __restrict__ partials,
                                                     float* __restrict__ out) {
    const int tid = threadIdx.x;
    double v = (double)partials[tid] + (double)partials[tid + 256];
    for (int off = 32; off > 0; off >>= 1) v += __shfl_down(v, off, 64);
    __shared__ double ws4[4];
    const int wid = tid >> 6;
    const int lane = tid & 63;
    if (lane == 0) ws4[wid] = v;
    __syncthreads();
    if (tid == 0) {
        const double total = ws4[0] + ws4[1] + ws4[2] + ws4[3];
        // x0.5 for ordered->unordered pairs, / num_triplets
        out[0] = (float)(total * 0.5 / 8290560.0);
    }
}

extern "C" void kernel_launch(void* const* d_in, const int* in_sizes, int n_in,
                              void* d_out, int out_size, void* d_ws, size_t ws_size,
                              hipStream_t stream) {
    const float* img = (const float*)d_in[0];  // img_tokens (256,768)
    const float* ehr = (const float*)d_in[1];  // ehr_tokens (256,768)
    float* out = (float*)d_out;

    float* dG = (float*)d_ws;            // img distances (256*256)
    float* dE = dG + NB * NB;            // ehr distances (256*256)
    float* partials = dE + NB * NB;      // 512 floats

    dist_kernel<<<dim3(2 * NTILES), 256, 0, stream>>>(img, ehr, dG, dE);
    triplet_kernel<<<dim3(2 * NB), 256, 0, stream>>>(dE, dG, partials);
    reduce_kernel<<<dim3(1), 256, 0, stream>>>(partials, out);
}